// Round 3
// baseline (301.734 us; speedup 1.0000x reference)
//
#include <hip/hip_runtime.h>
#include <hip/hip_bf16.h>

typedef __attribute__((ext_vector_type(8))) short bf16x8;
typedef __attribute__((ext_vector_type(4))) float f32x4;
typedef __attribute__((ext_vector_type(8))) unsigned short u16x8;

__device__ __forceinline__ unsigned short f2bf(float f) {
  union { float f; unsigned u; } v; v.f = f;
  unsigned r = v.u + 0x7FFFu + ((v.u >> 16) & 1u);
  return (unsigned short)(r >> 16);
}

__device__ __forceinline__ bf16x8 cvt8(f32x4 a, f32x4 b) {
  u16x8 o;
  o[0] = f2bf(a[0]); o[1] = f2bf(a[1]); o[2] = f2bf(a[2]); o[3] = f2bf(a[3]);
  o[4] = f2bf(b[0]); o[5] = f2bf(b[1]); o[6] = f2bf(b[2]); o[7] = f2bf(b[3]);
  union { u16x8 u; bf16x8 s; } c; c.u = o;
  return c.s;
}

// ---------------------------------------------------------------------------
// 128x128-tile NT GEMM with FUSED fp32->bf16 input conversion (reg-staged).
// A: [M][K] fp32 row-major, B: [N][K] fp32 row-major.
// Cb[m][n] = bf16( relu(acc + bias[n]) * (scale?scale[n]:1) )
// LDS layout identical to the proven round-0 kernel (XOR-swizzled 16B chunks);
// swizzle applied on the ds_write DEST (per-lane scatter allowed).
__global__ __launch_bounds__(256, 2)
void gemm128_f32in(const float* __restrict__ A, const float* __restrict__ B,
                   unsigned short* __restrict__ Cb,
                   const float* __restrict__ bias, const float* __restrict__ scale,
                   int M, int N, int K) {
  __shared__ unsigned short As[128 * 64];
  __shared__ unsigned short Bs[128 * 64];

  int nby = N >> 7;
  int nwg = gridDim.x;
  int wg = blockIdx.x;
  if ((nwg & 7) == 0) {
    int cpx = nwg >> 3;
    wg = (wg & 7) * cpx + (wg >> 3);
  }
  int bm = wg / nby, bn = wg % nby;
  int m0 = bm << 7, n0 = bn << 7;

  int tid = threadIdx.x;
  int w = tid >> 6, lane = tid & 63;
  int wave_m = (w >> 1) << 6;
  int wave_n = (w & 1) << 6;

  // staging: thread t handles row (i*32 + t>>3), source chunk (t&7) of 8 f32,
  // writes bf16x8 to swizzled LDS slot (t&7)^(row&7).
  int srow = tid >> 3, c8 = tid & 7;
  int slot = c8 ^ (srow & 7);
  const float* Ag = A + (size_t)(m0 + srow) * K + c8 * 8;
  const float* Bg = B + (size_t)(n0 + srow) * K + c8 * 8;
  int dst = srow * 64 + slot * 8;  // + i*2048 per sub-block of 32 rows

  int hi = lane >> 4, lo = lane & 15, e7 = lane & 7;
  int a_base[2], b_base[2];
#pragma unroll
  for (int kk = 0; kk < 2; ++kk) {
    int sl = ((kk << 2) + hi) ^ e7;
    a_base[kk] = (wave_m + lo) * 64 + sl * 8;
    b_base[kk] = (wave_n + lo) * 64 + sl * 8;
  }

  f32x4 acc[4][4] = {};
  f32x4 ra[4][2], rb[4][2];

#define LOADK(KT)                                                         \
  {                                                                       \
    _Pragma("unroll") for (int i_ = 0; i_ < 4; ++i_) {                    \
      const float* pa = Ag + (size_t)(KT) * 64 + (size_t)(i_ * 32) * K;   \
      const float* pb = Bg + (size_t)(KT) * 64 + (size_t)(i_ * 32) * K;   \
      ra[i_][0] = *(const f32x4*)pa; ra[i_][1] = *(const f32x4*)(pa + 4); \
      rb[i_][0] = *(const f32x4*)pb; rb[i_][1] = *(const f32x4*)(pb + 4); \
    }                                                                     \
  }

  LOADK(0);
  int ksteps = K >> 6;
  for (int kt = 0; kt < ksteps; ++kt) {
#pragma unroll
    for (int i = 0; i < 4; ++i) {
      *(bf16x8*)(&As[dst + i * 2048]) = cvt8(ra[i][0], ra[i][1]);
      *(bf16x8*)(&Bs[dst + i * 2048]) = cvt8(rb[i][0], rb[i][1]);
    }
    __syncthreads();
    if (kt + 1 < ksteps) LOADK(kt + 1);  // prefetch drains under MFMA

    bf16x8 afr[4][2], bfr[4][2];
#pragma unroll
    for (int kk = 0; kk < 2; ++kk) {
#pragma unroll
      for (int t2 = 0; t2 < 4; ++t2) {
        afr[t2][kk] = *(const bf16x8*)(&As[a_base[kk] + t2 * 1024]);
        bfr[t2][kk] = *(const bf16x8*)(&Bs[b_base[kk] + t2 * 1024]);
      }
    }
#pragma unroll
    for (int kk = 0; kk < 2; ++kk) {
#pragma unroll
      for (int mt = 0; mt < 4; ++mt) {
#pragma unroll
        for (int nt = 0; nt < 4; ++nt) {
          acc[mt][nt] = __builtin_amdgcn_mfma_f32_16x16x32_bf16(
              afr[mt][kk], bfr[nt][kk], acc[mt][nt], 0, 0, 0);
        }
      }
    }
    __syncthreads();
  }
#undef LOADK

  float bi[4], sc[4];
#pragma unroll
  for (int nt = 0; nt < 4; ++nt) {
    int n = n0 + wave_n + nt * 16 + lo;
    bi[nt] = bias ? bias[n] : 0.f;
    sc[nt] = scale ? scale[n] : 1.f;
  }
#pragma unroll
  for (int mt = 0; mt < 4; ++mt) {
#pragma unroll
    for (int r = 0; r < 4; ++r) {
      size_t m = (size_t)(m0 + wave_m + mt * 16 + hi * 4 + r);
      unsigned short* rowp = Cb + m * (size_t)N + (n0 + wave_n + lo);
#pragma unroll
      for (int nt = 0; nt < 4; ++nt) {
        float v = fmaxf(acc[mt][nt][r] + bi[nt], 0.f) * sc[nt];
        rowp[nt * 16] = f2bf(v);
      }
    }
  }
}

// ---------------------------------------------------------------------------
// PERSISTENT 256x256-tile, BK=64, 8-wave, 8-phase main GEMM.
// C[4096][32000] = A[4096][512] @ B[32000][512]^T + bconst[0]   (bf16 in, f32 out)
// Grid = 250 blocks = 2 bm-groups x 125 bn. Each block: fixed 256-col B panel
// (256KB, L2-hot after first tile), walks 8 A-tiles (bm = grp*8 .. grp*8+7).
// The 8-phase stage stream runs CONTINUOUSLY across tile boundaries; epilogue
// stores are fire-and-forget and drain under the next tile's MFMA phases.
__global__ __launch_bounds__(512, 2)
void gemm256_persist(const unsigned short* __restrict__ A,
                     const unsigned short* __restrict__ B,
                     float* __restrict__ Cf,
                     const float* __restrict__ bconst) {
  constexpr int K = 512;
  constexpr int N = 32000;
  constexpr int GT = (K >> 6) * 8;  // 64 global K-steps (8 tiles x 8)

  __shared__ unsigned short As[2][256 * 64];
  __shared__ unsigned short Bs[2][256 * 64];

  int bid = blockIdx.x;
  int grp = bid / 125;            // 0..1  -> bm tiles [grp*8, grp*8+8)
  int bn = bid - grp * 125;
  int n0 = bn << 8;
  int bm0 = grp << 3;

  int tid = threadIdx.x;
  int lane = tid & 63;
  int wid = tid >> 6;
  int wm = wid >> 2, wn = wid & 3;
  int lo = lane & 15, hi = lane >> 4;

  int srow = tid >> 3;
  int schunk = (tid & 7) ^ (srow & 7);
  const unsigned short* Asrc = A + (size_t)(bm0 * 256 + srow) * K + schunk * 8;
  const unsigned short* Bsrc = B + (size_t)(n0 + srow) * K + schunk * 8;
  const size_t tileA = (size_t)256 * K;
  int ldst = tid * 8;

  int soff[2];
  soff[0] = (hi ^ (lo & 7)) * 8;
  soff[1] = ((4 + hi) ^ (lo & 7)) * 8;
  int sA_row = (wm * 128 + lo) * 64;
  int sB_row = (wn * 64 + lo) * 64;

  float badd = bconst[0];
  f32x4 acc[8][4];
#pragma unroll
  for (int i = 0; i < 8; ++i)
#pragma unroll
    for (int jj = 0; jj < 4; ++jj) acc[i][jj] = (f32x4){0.f, 0.f, 0.f, 0.f};

  bf16x8 afr[4][2], bfr[2][2];

#define STAGE(SRC, LDSB, OFF)                                                   \
  {                                                                             \
    _Pragma("unroll") for (int i_ = 0; i_ < 4; ++i_) {                          \
      __builtin_amdgcn_global_load_lds(                                         \
          (const __attribute__((address_space(1))) void*)(                      \
              (SRC) + (OFF) + (size_t)(i_ * 64) * K),                           \
          (__attribute__((address_space(3))) void*)((LDSB) + i_ * 4096 + ldst), \
          16, 0, 0);                                                            \
    }                                                                           \
  }

#define PHASE(BUF, MH, NH, READA, STAGE_STMT, VM_STMT)                          \
  {                                                                             \
    STAGE_STMT;                                                                 \
    if (READA) {                                                                \
      _Pragma("unroll") for (int i_ = 0; i_ < 4; ++i_)                          \
        _Pragma("unroll") for (int kk_ = 0; kk_ < 2; ++kk_)                     \
          afr[i_][kk_] = *(const bf16x8*)(                                      \
              &As[BUF][sA_row + ((MH) * 4 + i_) * 1024 + soff[kk_]]);           \
    }                                                                           \
    _Pragma("unroll") for (int j_ = 0; j_ < 2; ++j_)                            \
      _Pragma("unroll") for (int kk_ = 0; kk_ < 2; ++kk_)                       \
        bfr[j_][kk_] = *(const bf16x8*)(                                        \
            &Bs[BUF][sB_row + ((NH) * 2 + j_) * 1024 + soff[kk_]]);             \
    __builtin_amdgcn_s_barrier();                                               \
    asm volatile("s_waitcnt lgkmcnt(0)" ::: "memory");                          \
    __builtin_amdgcn_sched_barrier(0);                                          \
    __builtin_amdgcn_s_setprio(1);                                              \
    _Pragma("unroll") for (int i_ = 0; i_ < 4; ++i_)                            \
      _Pragma("unroll") for (int j_ = 0; j_ < 2; ++j_)                          \
        _Pragma("unroll") for (int kk_ = 0; kk_ < 2; ++kk_)                     \
          acc[(MH) * 4 + i_][(NH) * 2 + j_] =                                   \
              __builtin_amdgcn_mfma_f32_16x16x32_bf16(                          \
                  afr[i_][kk_], bfr[j_][kk_],                                   \
                  acc[(MH) * 4 + i_][(NH) * 2 + j_], 0, 0, 0);                  \
    __builtin_amdgcn_s_setprio(0);                                              \
    VM_STMT;                                                                    \
    __builtin_amdgcn_s_barrier();                                               \
  }

  // prologue: stage global K-step 0 (tile 0) into buf0
  STAGE(Asrc, &As[0][0], (size_t)0);
  STAGE(Bsrc, &Bs[0][0], (size_t)0);
  asm volatile("s_waitcnt vmcnt(0)" ::: "memory");
  __builtin_amdgcn_s_barrier();

  for (int j = 0; j < GT / 2; ++j) {
    int g1 = 2 * j + 1, g2 = 2 * j + 2;
    size_t a1 = (size_t)(g1 >> 3) * tileA + (size_t)((g1 & 7) * 64);
    size_t b1 = (size_t)((g1 & 7) * 64);
    size_t a2 = (size_t)(g2 >> 3) * tileA + (size_t)((g2 & 7) * 64);
    size_t b2 = (size_t)((g2 & 7) * 64);
    bool more = g2 < GT;
    // phases 1-4: compute K-step 2j (buf0); stage K-step 2j+1 -> buf1
    PHASE(0, 0, 0, true,  { STAGE(Bsrc, &Bs[1][0], b1); }, {});
    PHASE(0, 0, 1, false, { STAGE(Asrc, &As[1][0], a1); }, {});
    PHASE(0, 1, 0, true,  {}, {});
    PHASE(0, 1, 1, false, {},
          { asm volatile("s_waitcnt vmcnt(0)" ::: "memory"); });
    // phases 5-8: compute K-step 2j+1 (buf1); stage K-step 2j+2 -> buf0
    PHASE(1, 0, 0, true,  { if (more) STAGE(Bsrc, &Bs[0][0], b2); }, {});
    PHASE(1, 0, 1, false, { if (more) STAGE(Asrc, &As[0][0], a2); }, {});
    PHASE(1, 1, 0, true,  {}, {});
    PHASE(1, 1, 1, false, {},
          { asm volatile("s_waitcnt vmcnt(0)" ::: "memory"); });

    if ((j & 3) == 3) {  // tile finished: fire-and-forget stores, re-zero acc
      int t = j >> 2;
      size_t mbase = (size_t)((bm0 + t) * 256 + wm * 128);
#pragma unroll
      for (int mt = 0; mt < 8; ++mt) {
#pragma unroll
        for (int r = 0; r < 4; ++r) {
          float* rowp = Cf + (mbase + mt * 16 + hi * 4 + r) * (size_t)N +
                        (n0 + wn * 64 + lo);
#pragma unroll
          for (int nt = 0; nt < 4; ++nt) {
            rowp[nt * 16] = acc[mt][nt][r] + badd;
          }
        }
      }
#pragma unroll
      for (int i = 0; i < 8; ++i)
#pragma unroll
        for (int jj = 0; jj < 4; ++jj) acc[i][jj] = (f32x4){0.f, 0.f, 0.f, 0.f};
    }
  }
#undef PHASE
#undef STAGE
}

extern "C" void kernel_launch(void* const* d_in, const int* in_sizes, int n_in,
                              void* d_out, int out_size, void* d_ws, size_t ws_size,
                              hipStream_t stream) {
  const float* h  = (const float*)d_in[0];  // [4096,1024]
  const float* l  = (const float*)d_in[1];  // [32000,512]
  const float* Wh = (const float*)d_in[2];  // [512,1024]
  const float* bh = (const float*)d_in[3];  // [512]
  const float* Wl = (const float*)d_in[4];  // [512,512]
  const float* bl = (const float*)d_in[5];  // [512]
  const float* w  = (const float*)d_in[6];  // [512]
  const float* b  = (const float*)d_in[7];  // [1]
  float* out = (float*)d_out;               // [4096,32000]

  char* ws = (char*)d_ws;
  unsigned short* hawbf = (unsigned short*)(ws + 0);        //  4,194,304 B
  unsigned short* labf  = (unsigned short*)(ws + 4194304);  // 32,768,000 B

  // GEMM1: hawbf = relu(h @ Wh^T + bh) * w   [4096,512], K=1024 (fp32 in)
  gemm128_f32in<<<dim3(32 * 4), dim3(256), 0, stream>>>(
      h, Wh, hawbf, bh, w, 4096, 512, 1024);
  // GEMM2: labf = relu(l @ Wl^T + bl)        [32000,512], K=512 (fp32 in)
  gemm128_f32in<<<dim3(250 * 4), dim3(256), 0, stream>>>(
      l, Wl, labf, bl, nullptr, 32000, 512, 512);
  // main: out = hawbf @ labf^T + b  [4096,32000], K=512 — persistent 8-phase
  gemm256_persist<<<dim3(250), dim3(512), 0, stream>>>(hawbf, labf, out, b);
}